// Round 6
// baseline (270.988 us; speedup 1.0000x reference)
//
#include <hip/hip_runtime.h>
#include <math.h>

#define NODES 50000
#define EDGES 800000
#define FIN   256
#define HD    64      // H*D = 4*16
#define NEG   0.2f

typedef __attribute__((ext_vector_type(8))) short bf16x8;
typedef __attribute__((ext_vector_type(4))) float f32x4;

// ---------------------------------------------------------------------------
// Split one fp32 value into hi/lo bf16 (truncation split; exact residual):
//   hi = top16(x), lo = top16(x - hi).  |err| of hi+lo ~ 2^-14 relative.
// ---------------------------------------------------------------------------
__device__ __forceinline__ unsigned pack_hi(unsigned a, unsigned b)
{ return (a >> 16) | (b & 0xFFFF0000u); }

__device__ __forceinline__ void split8(const float4 x01, const float4 x23,
                                       bf16x8& hi, bf16x8& lo)
{
    const float xs[8] = { x01.x, x01.y, x01.z, x01.w, x23.x, x23.y, x23.z, x23.w };
    union { unsigned w[4]; bf16x8 v; } H, L;
#pragma unroll
    for (int p = 0; p < 4; ++p) {
        const float a = xs[2 * p], b = xs[2 * p + 1];
        const unsigned ba = __float_as_uint(a), bb = __float_as_uint(b);
        H.w[p] = pack_hi(ba, bb);
        const float la = a - __uint_as_float(ba & 0xFFFF0000u);
        const float lb = b - __uint_as_float(bb & 0xFFFF0000u);
        L.w[p] = pack_hi(__float_as_uint(la), __float_as_uint(lb));
    }
    hi = H.v; lo = L.v;
}

// ---------------------------------------------------------------------------
// Prep: split Wsrc(rows 0..63) / Wdst(rows 64..127) into bf16 hi/lo planes.
// ---------------------------------------------------------------------------
__global__ void prep_b_kernel(const float* __restrict__ Wsrc,
                              const float* __restrict__ Wdst,
                              short* __restrict__ Bhi, short* __restrict__ Blo)
{
    const int i = blockIdx.x * 256 + threadIdx.x;       // 0..32767
    if (i >= 128 * FIN) return;
    const int row = i >> 8, k = i & 255;
    const float x = (row < 64) ? Wsrc[row * FIN + k] : Wdst[(row - 64) * FIN + k];
    const unsigned b = __float_as_uint(x);
    const float l = x - __uint_as_float(b & 0xFFFF0000u);
    Bhi[i] = (short)(b >> 16);
    Blo[i] = (short)(__float_as_uint(l) >> 16);
}

// ---------------------------------------------------------------------------
// MFMA projection: C[50000][128] = feat[50000][256] @ [Wsrc;Wdst]^T + bias.
// Block = 4 waves x 32 rows = 128 rows. Wave: 2 M-frags x 8 N-frags.
// Fragments are direct 16B global loads (k-contiguous per lane) — no LDS.
// 3-term split-bf16: Ahi*Bhi + Alo*Bhi + Ahi*Blo.
// ---------------------------------------------------------------------------
__global__ __launch_bounds__(256) void proj_mfma_kernel(
    const float* __restrict__ feat,
    const short* __restrict__ Bhi, const short* __restrict__ Blo,
    const float* __restrict__ bsrc, const float* __restrict__ bdst,
    float* __restrict__ fs, float* __restrict__ fd)
{
    const int t    = threadIdx.x;
    const int lane = t & 63;
    const int w    = t >> 6;                       // wave 0..3
    const int r0   = blockIdx.x * 128 + w * 32;    // wave's first row
    const int fr   = lane & 15;
    const int fq   = lane >> 4;                    // 0..3 (k-octet)

    int rowA0 = r0 + fr;       if (rowA0 >= NODES) rowA0 = NODES - 1;
    int rowA1 = r0 + 16 + fr;  if (rowA1 >= NODES) rowA1 = NODES - 1;
    const float* pA0 = feat + (size_t)rowA0 * FIN + fq * 8;
    const float* pA1 = feat + (size_t)rowA1 * FIN + fq * 8;
    const short* pBh = Bhi + fr * FIN + fq * 8;
    const short* pBl = Blo + fr * FIN + fq * 8;

    f32x4 acc[2][8];
#pragma unroll
    for (int m = 0; m < 2; ++m)
#pragma unroll
        for (int n = 0; n < 8; ++n) acc[m][n] = (f32x4){0.f, 0.f, 0.f, 0.f};

    for (int ks = 0; ks < 8; ++ks) {
        const int k0 = ks * 32;
        bf16x8 a0h, a0l, a1h, a1l;
        {
            const float4 x01 = *(const float4*)(pA0 + k0);
            const float4 x23 = *(const float4*)(pA0 + k0 + 4);
            split8(x01, x23, a0h, a0l);
        }
        {
            const float4 x01 = *(const float4*)(pA1 + k0);
            const float4 x23 = *(const float4*)(pA1 + k0 + 4);
            split8(x01, x23, a1h, a1l);
        }
#pragma unroll
        for (int nf = 0; nf < 8; ++nf) {
            const bf16x8 bh = *(const bf16x8*)(pBh + nf * 16 * FIN + k0);
            const bf16x8 bl = *(const bf16x8*)(pBl + nf * 16 * FIN + k0);
            acc[0][nf] = __builtin_amdgcn_mfma_f32_16x16x32_bf16(a0h, bh, acc[0][nf], 0, 0, 0);
            acc[1][nf] = __builtin_amdgcn_mfma_f32_16x16x32_bf16(a1h, bh, acc[1][nf], 0, 0, 0);
            acc[0][nf] = __builtin_amdgcn_mfma_f32_16x16x32_bf16(a0l, bh, acc[0][nf], 0, 0, 0);
            acc[1][nf] = __builtin_amdgcn_mfma_f32_16x16x32_bf16(a1l, bh, acc[1][nf], 0, 0, 0);
            acc[0][nf] = __builtin_amdgcn_mfma_f32_16x16x32_bf16(a0h, bl, acc[0][nf], 0, 0, 0);
            acc[1][nf] = __builtin_amdgcn_mfma_f32_16x16x32_bf16(a1h, bl, acc[1][nf], 0, 0, 0);
        }
    }

    // epilogue: bias + store.  D: row = fq*4+r, col = fr (per m89/m91 mapping)
#pragma unroll
    for (int nf = 0; nf < 8; ++nf) {
        float* outp = (nf < 4) ? fs : fd;
        const float bias = ((nf < 4) ? bsrc : bdst)[(nf & 3) * 16 + fr];
        const int c = (nf & 3) * 16 + fr;
#pragma unroll
        for (int mf = 0; mf < 2; ++mf) {
#pragma unroll
            for (int r = 0; r < 4; ++r) {
                const int row = r0 + mf * 16 + fq * 4 + r;
                if (row < NODES)
                    outp[(size_t)row * HD + c] = acc[mf][nf][r] + bias;
            }
        }
    }
}

// ---------------------------------------------------------------------------
// CSR build: histogram -> scan1 (per-1024 chunk) -> scan3 (adds raw partials)
// ---------------------------------------------------------------------------
__global__ void hist_kernel(const int* __restrict__ dst, int* __restrict__ deg)
{
    const int i = blockIdx.x * blockDim.x + threadIdx.x;
    if (i < EDGES) atomicAdd(&deg[dst[i]], 1);
}

__global__ void scan1_kernel(const int* __restrict__ deg, int* __restrict__ offs,
                             int* __restrict__ part)
{
    __shared__ int lds[256];
    const int t  = threadIdx.x;
    const int i0 = blockIdx.x * 1024 + t * 4;
    int v[4];
#pragma unroll
    for (int k = 0; k < 4; ++k) v[k] = (i0 + k < NODES) ? deg[i0 + k] : 0;
    const int tsum = v[0] + v[1] + v[2] + v[3];
    lds[t] = tsum;
    __syncthreads();
    for (int off = 1; off < 256; off <<= 1) {
        const int x = (t >= off) ? lds[t - off] : 0;
        __syncthreads();
        lds[t] += x;
        __syncthreads();
    }
    const int excl = lds[t] - tsum;
    int run = excl;
#pragma unroll
    for (int k = 0; k < 4; ++k) {
        if (i0 + k < NODES) offs[i0 + k] = run;
        run += v[k];
    }
    if (t == 255) part[blockIdx.x] = lds[255];   // inclusive chunk total
}

__global__ void scan3_kernel(int* __restrict__ offs, const int* __restrict__ part,
                             int* __restrict__ cursor)
{
    const int i = blockIdx.x * blockDim.x + threadIdx.x;
    const int pidx = blockIdx.x >> 2;            // block-uniform chunk index
    int add = 0;
    for (int b = 0; b < pidx; ++b) add += part[b];
    if (i < NODES) {
        const int val = offs[i] + add;
        offs[i]   = val;
        cursor[i] = val;
    }
    if (i == 0) offs[NODES] = EDGES;
}

__global__ void scatter_kernel(const int* __restrict__ src, const int* __restrict__ dst,
                               int* __restrict__ cursor, int* __restrict__ csr)
{
    const int e = blockIdx.x * blockDim.x + threadIdx.x;
    if (e < EDGES) {
        const int d   = dst[e];
        const int pos = atomicAdd(&cursor[d], 1);
        csr[pos] = src[e];
    }
}

// ---------------------------------------------------------------------------
// Per-destination-node GAT: one wave per node, lane = h*16+d.
// No max-subtraction (scores bounded; exp(s)/sum exp(s) identical math).
// Head reduce via DPP (VALU), edge broadcast via readlane, 4-edge unroll.
// ---------------------------------------------------------------------------
__device__ __forceinline__ float head_sum16(float x)
{
    x += __int_as_float(__builtin_amdgcn_update_dpp(0, __float_as_int(x), 0xB1,  0xf, 0xf, true)); // ^1
    x += __int_as_float(__builtin_amdgcn_update_dpp(0, __float_as_int(x), 0x4E,  0xf, 0xf, true)); // ^2
    x += __int_as_float(__builtin_amdgcn_update_dpp(0, __float_as_int(x), 0x141, 0xf, 0xf, true)); // half-mirror
    x += __int_as_float(__builtin_amdgcn_update_dpp(0, __float_as_int(x), 0x140, 0xf, 0xf, true)); // mirror
    return x;
}

__global__ __launch_bounds__(256) void gat_kernel(
    const float* __restrict__ fs, const float* __restrict__ fd,
    const float* __restrict__ attn,
    const int* __restrict__ offs, const int* __restrict__ csr,
    float* __restrict__ out)
{
    const int wid  = (blockIdx.x * blockDim.x + threadIdx.x) >> 6;  // node id
    const int lane = threadIdx.x & 63;
    if (wid >= NODES) return;

    const float er = fd[(size_t)wid * HD + lane];
    const float aw = attn[lane];
    const int start = __builtin_amdgcn_readfirstlane(offs[wid]);
    const int end   = __builtin_amdgcn_readfirstlane(offs[wid + 1]);

    float s = 0.f, acc = 0.f;

    for (int base = start; base < end; base += 64) {
        const int rem = end - base;
        const int cnt = rem < 64 ? rem : 64;
        int srcv = 0;
        if (lane < cnt) srcv = csr[base + lane];

        int j = 0;
        for (; j + 4 <= cnt; j += 4) {
            const int i0 = __builtin_amdgcn_readlane(srcv, j + 0);
            const int i1 = __builtin_amdgcn_readlane(srcv, j + 1);
            const int i2 = __builtin_amdgcn_readlane(srcv, j + 2);
            const int i3 = __builtin_amdgcn_readlane(srcv, j + 3);
            const float el0 = fs[(size_t)i0 * HD + lane];
            const float el1 = fs[(size_t)i1 * HD + lane];
            const float el2 = fs[(size_t)i2 * HD + lane];
            const float el3 = fs[(size_t)i3 * HD + lane];
            const float t0 = el0 + er, t1 = el1 + er, t2 = el2 + er, t3 = el3 + er;
            const float e0 = fmaf(NEG, fminf(t0, 0.f), fmaxf(t0, 0.f));
            const float e1 = fmaf(NEG, fminf(t1, 0.f), fmaxf(t1, 0.f));
            const float e2 = fmaf(NEG, fminf(t2, 0.f), fmaxf(t2, 0.f));
            const float e3 = fmaf(NEG, fminf(t3, 0.f), fmaxf(t3, 0.f));
            const float p0 = head_sum16(e0 * aw);
            const float p1 = head_sum16(e1 * aw);
            const float p2 = head_sum16(e2 * aw);
            const float p3 = head_sum16(e3 * aw);
            const float pe0 = __expf(p0);
            const float pe1 = __expf(p1);
            const float pe2 = __expf(p2);
            const float pe3 = __expf(p3);
            s += (pe0 + pe1) + (pe2 + pe3);
            acc = fmaf(pe0, el0, fmaf(pe1, el1, fmaf(pe2, el2, fmaf(pe3, el3, acc))));
        }
        for (; j < cnt; ++j) {
            const int i0 = __builtin_amdgcn_readlane(srcv, j);
            const float el0 = fs[(size_t)i0 * HD + lane];
            const float t0 = el0 + er;
            const float e0 = fmaf(NEG, fminf(t0, 0.f), fmaxf(t0, 0.f));
            const float pe0 = __expf(head_sum16(e0 * aw));
            s += pe0;
            acc = fmaf(pe0, el0, acc);
        }
    }
    out[(size_t)wid * HD + lane] = (end > start) ? (acc / s) : 0.f;
}

// ---------------------------------------------------------------------------
extern "C" void kernel_launch(void* const* d_in, const int* in_sizes, int n_in,
                              void* d_out, int out_size, void* d_ws, size_t ws_size,
                              hipStream_t stream)
{
    const float* feat = (const float*)d_in[0];
    const int*   src  = (const int*)  d_in[1];
    const int*   dst  = (const int*)  d_in[2];
    const float* Wsrc = (const float*)d_in[3];
    const float* bsrc = (const float*)d_in[4];
    const float* Wdst = (const float*)d_in[5];
    const float* bdst = (const float*)d_in[6];
    const float* attn = (const float*)d_in[7];
    float* out = (float*)d_out;

    // workspace layout (~29.7 MB)
    float* fs     = (float*)d_ws;                    // N*64 f32
    float* fd     = fs + (size_t)NODES * HD;         // N*64 f32
    int*   offs   = (int*)(fd + (size_t)NODES * HD); // N+1 (+pad)
    int*   deg    = offs + (NODES + 16);             // N
    int*   cursor = deg + NODES;                     // N
    int*   part   = cursor + NODES;                  // 64
    int*   csr    = part + 64;                       // E
    short* Bhi    = (short*)(csr + EDGES);           // 128*256 bf16
    short* Blo    = Bhi + 128 * FIN;                 // 128*256 bf16

    const int scan_blocks = (NODES + 1023) / 1024;   // 49

    hipMemsetAsync(deg, 0, NODES * sizeof(int), stream);

    prep_b_kernel<<<(128 * FIN + 255) / 256, 256, 0, stream>>>(Wsrc, Wdst, Bhi, Blo);
    proj_mfma_kernel<<<(NODES + 127) / 128, 256, 0, stream>>>(feat, Bhi, Blo, bsrc, bdst, fs, fd);
    hist_kernel<<<(EDGES + 255) / 256, 256, 0, stream>>>(dst, deg);
    scan1_kernel<<<scan_blocks, 256, 0, stream>>>(deg, offs, part);
    scan3_kernel<<<(NODES + 255) / 256, 256, 0, stream>>>(offs, part, cursor);
    scatter_kernel<<<(EDGES + 255) / 256, 256, 0, stream>>>(src, dst, cursor, csr);
    gat_kernel<<<((size_t)NODES * 64 + 255) / 256, 256, 0, stream>>>(fs, fd, attn, offs, csr, out);
}

// Round 7
// 248.848 us; speedup vs baseline: 1.0890x; 1.0890x over previous
//
#include <hip/hip_runtime.h>
#include <math.h>

#define NODES 50000
#define EDGES 800000
#define FIN   256
#define HD    64      // H*D = 4*16
#define NEG   0.2f

typedef __attribute__((ext_vector_type(8))) short bf16x8;
typedef __attribute__((ext_vector_type(4))) float f32x4;

// ---------------------------------------------------------------------------
// Split fp32 -> hi/lo bf16 (truncation split; exact residual).
// ---------------------------------------------------------------------------
__device__ __forceinline__ unsigned pack_hi(unsigned a, unsigned b)
{ return (a >> 16) | (b & 0xFFFF0000u); }

__device__ __forceinline__ void split8(const float4 x01, const float4 x23,
                                       bf16x8& hi, bf16x8& lo)
{
    const float xs[8] = { x01.x, x01.y, x01.z, x01.w, x23.x, x23.y, x23.z, x23.w };
    union { unsigned w[4]; bf16x8 v; } H, L;
#pragma unroll
    for (int p = 0; p < 4; ++p) {
        const float a = xs[2 * p], b = xs[2 * p + 1];
        const unsigned ba = __float_as_uint(a), bb = __float_as_uint(b);
        H.w[p] = pack_hi(ba, bb);
        const float la = a - __uint_as_float(ba & 0xFFFF0000u);
        const float lb = b - __uint_as_float(bb & 0xFFFF0000u);
        L.w[p] = pack_hi(__float_as_uint(la), __float_as_uint(lb));
    }
    hi = H.v; lo = L.v;
}

// ---------------------------------------------------------------------------
// Prep: split Wsrc(rows 0..63) / Wdst(rows 64..127) into bf16 hi/lo planes.
// ---------------------------------------------------------------------------
__global__ void prep_b_kernel(const float* __restrict__ Wsrc,
                              const float* __restrict__ Wdst,
                              short* __restrict__ Bhi, short* __restrict__ Blo)
{
    const int i = blockIdx.x * 256 + threadIdx.x;       // 0..32767
    if (i >= 128 * FIN) return;
    const int row = i >> 8, k = i & 255;
    const float x = (row < 64) ? Wsrc[row * FIN + k] : Wdst[(row - 64) * FIN + k];
    const unsigned b = __float_as_uint(x);
    const float l = x - __uint_as_float(b & 0xFFFF0000u);
    Bhi[i] = (short)(b >> 16);
    Blo[i] = (short)(__float_as_uint(l) >> 16);
}

// ---------------------------------------------------------------------------
// MFMA projection: C[50000][128] = feat[50000][256] @ [Wsrc;Wdst]^T + bias.
// Block = 4 waves x 32 rows = 128 rows, all 128 cols per wave.
// B staged in LDS (double-buffered per 32-k slice, shared by 4 waves);
// A register-prefetched one slice ahead. 3-term split-bf16 MFMA.
// LDS unit layout [plane][fq*128+col] * 16B: ds_read_b128 at the structural
// b128 minimum (8 rows/bank, no extra conflicts).
// ---------------------------------------------------------------------------
__global__ __launch_bounds__(256) void proj_mfma_kernel(
    const float* __restrict__ feat,
    const short* __restrict__ Bhi, const short* __restrict__ Blo,
    const float* __restrict__ bsrc, const float* __restrict__ bdst,
    float* __restrict__ fs, float* __restrict__ fd)
{
    __shared__ short sB[2][2][512 * 8];            // [buf][plane][unit*8] 32 KB

    const int t    = threadIdx.x;
    const int lane = t & 63;
    const int w    = t >> 6;                       // wave 0..3
    const int r0   = blockIdx.x * 128 + w * 32;    // wave's first row
    const int fr   = lane & 15;
    const int fq   = lane >> 4;                    // k-octet 0..3
    const int fragu = fq * 128 + fr;               // LDS unit base for frags

    // staging ids: thread t stages units t and t+256 per plane
    const int colu = t & 127;
    const int fq0  = t >> 7;                       // 0..1
    const int fq1  = fq0 + 2;                      // 2..3

    int rowA0 = r0 + fr;       if (rowA0 >= NODES) rowA0 = NODES - 1;
    int rowA1 = r0 + 16 + fr;  if (rowA1 >= NODES) rowA1 = NODES - 1;
    const float* pA0 = feat + (size_t)rowA0 * FIN + fq * 8;
    const float* pA1 = feat + (size_t)rowA1 * FIN + fq * 8;

    f32x4 acc[2][8];
#pragma unroll
    for (int m = 0; m < 2; ++m)
#pragma unroll
        for (int n = 0; n < 8; ++n) acc[m][n] = (f32x4){0.f, 0.f, 0.f, 0.f};

    float4 bs00, bs01, bs10, bs11;                 // B stage regs
    float4 ac0A, ac0B, ac1A, ac1B;                 // A current
    float4 an0A, an0B, an1A, an1B;                 // A next

#define B_ISSUE(kslice) do {                                                  \
        const size_t o0 = (size_t)colu * FIN + (kslice) * 32 + fq0 * 8;       \
        const size_t o1 = (size_t)colu * FIN + (kslice) * 32 + fq1 * 8;       \
        bs00 = *(const float4*)(Bhi + o0);  bs01 = *(const float4*)(Bhi + o1);\
        bs10 = *(const float4*)(Blo + o0);  bs11 = *(const float4*)(Blo + o1);\
    } while (0)

#define B_WRITE(buf) do {                                                     \
        *(float4*)&sB[buf][0][(size_t)t * 8]         = bs00;                  \
        *(float4*)&sB[buf][0][(size_t)(t + 256) * 8] = bs01;                  \
        *(float4*)&sB[buf][1][(size_t)t * 8]         = bs10;                  \
        *(float4*)&sB[buf][1][(size_t)(t + 256) * 8] = bs11;                  \
    } while (0)

#define A_LOAD(d0A, d0B, d1A, d1B, kslice) do {                               \
        d0A = *(const float4*)(pA0 + (kslice) * 32);                          \
        d0B = *(const float4*)(pA0 + (kslice) * 32 + 4);                      \
        d1A = *(const float4*)(pA1 + (kslice) * 32);                          \
        d1B = *(const float4*)(pA1 + (kslice) * 32 + 4);                      \
    } while (0)

#define COMPUTE(buf, A0H, A0L, A1H, A1L) do {                                 \
        _Pragma("unroll")                                                     \
        for (int nf = 0; nf < 8; ++nf) {                                      \
            const bf16x8 bh = *(const bf16x8*)&sB[buf][0][(fragu + nf*16)*8]; \
            const bf16x8 bl = *(const bf16x8*)&sB[buf][1][(fragu + nf*16)*8]; \
            acc[0][nf] = __builtin_amdgcn_mfma_f32_16x16x32_bf16(A0H, bh, acc[0][nf], 0, 0, 0); \
            acc[1][nf] = __builtin_amdgcn_mfma_f32_16x16x32_bf16(A1H, bh, acc[1][nf], 0, 0, 0); \
            acc[0][nf] = __builtin_amdgcn_mfma_f32_16x16x32_bf16(A0L, bh, acc[0][nf], 0, 0, 0); \
            acc[1][nf] = __builtin_amdgcn_mfma_f32_16x16x32_bf16(A1L, bh, acc[1][nf], 0, 0, 0); \
            acc[0][nf] = __builtin_amdgcn_mfma_f32_16x16x32_bf16(A0H, bl, acc[0][nf], 0, 0, 0); \
            acc[1][nf] = __builtin_amdgcn_mfma_f32_16x16x32_bf16(A1H, bl, acc[1][nf], 0, 0, 0); \
        } } while (0)

    // prologue: stage slice 0, load A slice 0
    B_ISSUE(0);
    A_LOAD(ac0A, ac0B, ac1A, ac1B, 0);
    B_WRITE(0);
    __syncthreads();

    for (int ks2 = 0; ks2 < 8; ks2 += 2) {
        const int k1 = (ks2 + 1 < 7) ? ks2 + 1 : 7;
        const int k2 = (ks2 + 2 < 7) ? ks2 + 2 : 7;
        bf16x8 a0h, a0l, a1h, a1l;

        // even phase: compute slice ks2 from buf0; stage k1 -> buf1
        B_ISSUE(k1);
        A_LOAD(an0A, an0B, an1A, an1B, k1);
        split8(ac0A, ac0B, a0h, a0l);
        split8(ac1A, ac1B, a1h, a1l);
        COMPUTE(0, a0h, a0l, a1h, a1l);
        B_WRITE(1);
        __syncthreads();

        // odd phase: compute slice ks2+1 from buf1; stage k2 -> buf0
        B_ISSUE(k2);
        A_LOAD(ac0A, ac0B, ac1A, ac1B, k2);
        split8(an0A, an0B, a0h, a0l);
        split8(an1A, an1B, a1h, a1l);
        COMPUTE(1, a0h, a0l, a1h, a1l);
        B_WRITE(0);
        __syncthreads();
    }

    // epilogue: bias + store.  D: row = fq*4+r, col = fr (m89/m91 mapping)
#pragma unroll
    for (int nf = 0; nf < 8; ++nf) {
        float* outp = (nf < 4) ? fs : fd;
        const float bias = ((nf < 4) ? bsrc : bdst)[(nf & 3) * 16 + fr];
        const int c = (nf & 3) * 16 + fr;
#pragma unroll
        for (int mf = 0; mf < 2; ++mf) {
#pragma unroll
            for (int r = 0; r < 4; ++r) {
                const int row = r0 + mf * 16 + fq * 4 + r;
                if (row < NODES)
                    outp[(size_t)row * HD + c] = acc[mf][nf][r] + bias;
            }
        }
    }
#undef B_ISSUE
#undef B_WRITE
#undef A_LOAD
#undef COMPUTE
}

// ---------------------------------------------------------------------------
// CSR build: histogram -> scan1 (per-1024 chunk) -> scan3 (adds raw partials)
// ---------------------------------------------------------------------------
__global__ void hist_kernel(const int* __restrict__ dst, int* __restrict__ deg)
{
    const int i = blockIdx.x * blockDim.x + threadIdx.x;
    if (i < EDGES) atomicAdd(&deg[dst[i]], 1);
}

__global__ void scan1_kernel(const int* __restrict__ deg, int* __restrict__ offs,
                             int* __restrict__ part)
{
    __shared__ int lds[256];
    const int t  = threadIdx.x;
    const int i0 = blockIdx.x * 1024 + t * 4;
    int v[4];
#pragma unroll
    for (int k = 0; k < 4; ++k) v[k] = (i0 + k < NODES) ? deg[i0 + k] : 0;
    const int tsum = v[0] + v[1] + v[2] + v[3];
    lds[t] = tsum;
    __syncthreads();
    for (int off = 1; off < 256; off <<= 1) {
        const int x = (t >= off) ? lds[t - off] : 0;
        __syncthreads();
        lds[t] += x;
        __syncthreads();
    }
    const int excl = lds[t] - tsum;
    int run = excl;
#pragma unroll
    for (int k = 0; k < 4; ++k) {
        if (i0 + k < NODES) offs[i0 + k] = run;
        run += v[k];
    }
    if (t == 255) part[blockIdx.x] = lds[255];   // inclusive chunk total
}

__global__ void scan3_kernel(int* __restrict__ offs, const int* __restrict__ part,
                             int* __restrict__ cursor)
{
    const int i = blockIdx.x * blockDim.x + threadIdx.x;
    const int pidx = blockIdx.x >> 2;            // block-uniform chunk index
    int add = 0;
    for (int b = 0; b < pidx; ++b) add += part[b];
    if (i < NODES) {
        const int val = offs[i] + add;
        offs[i]   = val;
        cursor[i] = val;
    }
    if (i == 0) offs[NODES] = EDGES;
}

__global__ void scatter_kernel(const int* __restrict__ src, const int* __restrict__ dst,
                               int* __restrict__ cursor,
                               unsigned short* __restrict__ csr)
{
    const int e = blockIdx.x * blockDim.x + threadIdx.x;
    if (e < EDGES) {
        const int d   = dst[e];
        const int pos = atomicAdd(&cursor[d], 1);
        csr[pos] = (unsigned short)src[e];
    }
}

// ---------------------------------------------------------------------------
// Per-destination-node GAT: one wave per node, lane = h*16+d.
// No max-subtraction (scores bounded; exp(s)/sum exp(s) identical math).
// Head reduce via DPP (VALU), edge broadcast via readlane, 4-edge unroll.
// ---------------------------------------------------------------------------
__device__ __forceinline__ float head_sum16(float x)
{
    x += __int_as_float(__builtin_amdgcn_update_dpp(0, __float_as_int(x), 0xB1,  0xf, 0xf, true)); // ^1
    x += __int_as_float(__builtin_amdgcn_update_dpp(0, __float_as_int(x), 0x4E,  0xf, 0xf, true)); // ^2
    x += __int_as_float(__builtin_amdgcn_update_dpp(0, __float_as_int(x), 0x141, 0xf, 0xf, true)); // half-mirror
    x += __int_as_float(__builtin_amdgcn_update_dpp(0, __float_as_int(x), 0x140, 0xf, 0xf, true)); // mirror
    return x;
}

__global__ __launch_bounds__(256) void gat_kernel(
    const float* __restrict__ fs, const float* __restrict__ fd,
    const float* __restrict__ attn,
    const int* __restrict__ offs, const unsigned short* __restrict__ csr,
    float* __restrict__ out)
{
    const int wid  = (blockIdx.x * blockDim.x + threadIdx.x) >> 6;  // node id
    const int lane = threadIdx.x & 63;
    if (wid >= NODES) return;

    const float er = fd[(size_t)wid * HD + lane];
    const float aw = attn[lane];
    const int start = __builtin_amdgcn_readfirstlane(offs[wid]);
    const int end   = __builtin_amdgcn_readfirstlane(offs[wid + 1]);

    float s = 0.f, acc = 0.f;

    for (int base = start; base < end; base += 64) {
        const int rem = end - base;
        const int cnt = rem < 64 ? rem : 64;
        int srcv = 0;
        if (lane < cnt) srcv = (int)csr[base + lane];

        int j = 0;
        for (; j + 4 <= cnt; j += 4) {
            const int i0 = __builtin_amdgcn_readlane(srcv, j + 0);
            const int i1 = __builtin_amdgcn_readlane(srcv, j + 1);
            const int i2 = __builtin_amdgcn_readlane(srcv, j + 2);
            const int i3 = __builtin_amdgcn_readlane(srcv, j + 3);
            const float el0 = fs[(size_t)i0 * HD + lane];
            const float el1 = fs[(size_t)i1 * HD + lane];
            const float el2 = fs[(size_t)i2 * HD + lane];
            const float el3 = fs[(size_t)i3 * HD + lane];
            const float t0 = el0 + er, t1 = el1 + er, t2 = el2 + er, t3 = el3 + er;
            const float e0 = fmaf(NEG, fminf(t0, 0.f), fmaxf(t0, 0.f));
            const float e1 = fmaf(NEG, fminf(t1, 0.f), fmaxf(t1, 0.f));
            const float e2 = fmaf(NEG, fminf(t2, 0.f), fmaxf(t2, 0.f));
            const float e3 = fmaf(NEG, fminf(t3, 0.f), fmaxf(t3, 0.f));
            const float p0 = head_sum16(e0 * aw);
            const float p1 = head_sum16(e1 * aw);
            const float p2 = head_sum16(e2 * aw);
            const float p3 = head_sum16(e3 * aw);
            const float pe0 = __expf(p0);
            const float pe1 = __expf(p1);
            const float pe2 = __expf(p2);
            const float pe3 = __expf(p3);
            s += (pe0 + pe1) + (pe2 + pe3);
            acc = fmaf(pe0, el0, fmaf(pe1, el1, fmaf(pe2, el2, fmaf(pe3, el3, acc))));
        }
        for (; j < cnt; ++j) {
            const int i0 = __builtin_amdgcn_readlane(srcv, j);
            const float el0 = fs[(size_t)i0 * HD + lane];
            const float t0 = el0 + er;
            const float e0 = fmaf(NEG, fminf(t0, 0.f), fmaxf(t0, 0.f));
            const float pe0 = __expf(head_sum16(e0 * aw));
            s += pe0;
            acc = fmaf(pe0, el0, acc);
        }
    }
    out[(size_t)wid * HD + lane] = (end > start) ? (acc / s) : 0.f;
}

// ---------------------------------------------------------------------------
extern "C" void kernel_launch(void* const* d_in, const int* in_sizes, int n_in,
                              void* d_out, int out_size, void* d_ws, size_t ws_size,
                              hipStream_t stream)
{
    const float* feat = (const float*)d_in[0];
    const int*   src  = (const int*)  d_in[1];
    const int*   dst  = (const int*)  d_in[2];
    const float* Wsrc = (const float*)d_in[3];
    const float* bsrc = (const float*)d_in[4];
    const float* Wdst = (const float*)d_in[5];
    const float* bdst = (const float*)d_in[6];
    const float* attn = (const float*)d_in[7];
    float* out = (float*)d_out;

    // workspace layout (~27.9 MB)
    float* fs     = (float*)d_ws;                    // N*64 f32
    float* fd     = fs + (size_t)NODES * HD;         // N*64 f32
    int*   offs   = (int*)(fd + (size_t)NODES * HD); // N+1 (+pad)
    int*   deg    = offs + (NODES + 16);             // N
    int*   cursor = deg + NODES;                     // N
    int*   part   = cursor + NODES;                  // 64
    unsigned short* csr = (unsigned short*)(part + 64); // E ushort
    short* Bhi    = (short*)(csr + EDGES);           // 128*256 bf16
    short* Blo    = Bhi + 128 * FIN;                 // 128*256 bf16

    const int scan_blocks = (NODES + 1023) / 1024;   // 49

    hipMemsetAsync(deg, 0, NODES * sizeof(int), stream);

    prep_b_kernel<<<(128 * FIN + 255) / 256, 256, 0, stream>>>(Wsrc, Wdst, Bhi, Blo);
    proj_mfma_kernel<<<(NODES + 127) / 128, 256, 0, stream>>>(feat, Bhi, Blo, bsrc, bdst, fs, fd);
    hist_kernel<<<(EDGES + 255) / 256, 256, 0, stream>>>(dst, deg);
    scan1_kernel<<<scan_blocks, 256, 0, stream>>>(deg, offs, part);
    scan3_kernel<<<(NODES + 255) / 256, 256, 0, stream>>>(offs, part, cursor);
    scatter_kernel<<<(EDGES + 255) / 256, 256, 0, stream>>>(src, dst, cursor, csr);
    gat_kernel<<<((size_t)NODES * 64 + 255) / 256, 256, 0, stream>>>(fs, fd, attn, offs, csr, out);
}

// Round 8
// 242.943 us; speedup vs baseline: 1.1154x; 1.0243x over previous
//
#include <hip/hip_runtime.h>
#include <math.h>

#define NODES 50000
#define EDGES 800000
#define FIN   256
#define HD    64      // H*D = 4*16
#define NEG   0.2f

#define PROJ_BLOCKS 782          // ceil(50000/64) : 64 rows per block
#define SCAT_BLOCKS 3125         // ceil(800000/256)
#define PREP_BLOCKS 128          // 32768/256
#define HIST_BLOCKS 3125

typedef __attribute__((ext_vector_type(8))) short bf16x8;
typedef __attribute__((ext_vector_type(4))) float f32x4;

// ---------------------------------------------------------------------------
// Split fp32 -> hi/lo bf16 (truncation split; exact residual).
// ---------------------------------------------------------------------------
__device__ __forceinline__ unsigned pack_hi(unsigned a, unsigned b)
{ return (a >> 16) | (b & 0xFFFF0000u); }

__device__ __forceinline__ void split8(const float4 x01, const float4 x23,
                                       bf16x8& hi, bf16x8& lo)
{
    const float xs[8] = { x01.x, x01.y, x01.z, x01.w, x23.x, x23.y, x23.z, x23.w };
    union { unsigned w[4]; bf16x8 v; } H, L;
#pragma unroll
    for (int p = 0; p < 4; ++p) {
        const float a = xs[2 * p], b = xs[2 * p + 1];
        const unsigned ba = __float_as_uint(a), bb = __float_as_uint(b);
        H.w[p] = pack_hi(ba, bb);
        const float la = a - __uint_as_float(ba & 0xFFFF0000u);
        const float lb = b - __uint_as_float(bb & 0xFFFF0000u);
        L.w[p] = pack_hi(__float_as_uint(la), __float_as_uint(lb));
    }
    hi = H.v; lo = L.v;
}

// ---------------------------------------------------------------------------
// Fused: prep_b (blocks 0..127) || hist (blocks 128..3252). Independent work.
// ---------------------------------------------------------------------------
__global__ void prep_hist_kernel(const float* __restrict__ Wsrc,
                                 const float* __restrict__ Wdst,
                                 short* __restrict__ Bhi, short* __restrict__ Blo,
                                 const int* __restrict__ dst, int* __restrict__ deg)
{
    const int b = blockIdx.x;
    if (b < PREP_BLOCKS) {
        const int i = b * 256 + threadIdx.x;            // 0..32767
        const int row = i >> 8, k = i & 255;
        const float x = (row < 64) ? Wsrc[row * FIN + k] : Wdst[(row - 64) * FIN + k];
        const unsigned bb = __float_as_uint(x);
        const float l = x - __uint_as_float(bb & 0xFFFF0000u);
        Bhi[i] = (short)(bb >> 16);
        Blo[i] = (short)(__float_as_uint(l) >> 16);
    } else {
        const int e = (b - PREP_BLOCKS) * 256 + threadIdx.x;
        if (e < EDGES) atomicAdd(&deg[dst[e]], 1);
    }
}

// ---------------------------------------------------------------------------
// CSR scan: scan1 (per-1024 chunk) -> scan3 (adds raw partials)
// ---------------------------------------------------------------------------
__global__ void scan1_kernel(const int* __restrict__ deg, int* __restrict__ offs,
                             int* __restrict__ part)
{
    __shared__ int lds[256];
    const int t  = threadIdx.x;
    const int i0 = blockIdx.x * 1024 + t * 4;
    int v[4];
#pragma unroll
    for (int k = 0; k < 4; ++k) v[k] = (i0 + k < NODES) ? deg[i0 + k] : 0;
    const int tsum = v[0] + v[1] + v[2] + v[3];
    lds[t] = tsum;
    __syncthreads();
    for (int off = 1; off < 256; off <<= 1) {
        const int x = (t >= off) ? lds[t - off] : 0;
        __syncthreads();
        lds[t] += x;
        __syncthreads();
    }
    const int excl = lds[t] - tsum;
    int run = excl;
#pragma unroll
    for (int k = 0; k < 4; ++k) {
        if (i0 + k < NODES) offs[i0 + k] = run;
        run += v[k];
    }
    if (t == 255) part[blockIdx.x] = lds[255];   // inclusive chunk total
}

__global__ void scan3_kernel(int* __restrict__ offs, const int* __restrict__ part,
                             int* __restrict__ cursor)
{
    const int i = blockIdx.x * blockDim.x + threadIdx.x;
    const int pidx = blockIdx.x >> 2;            // block-uniform chunk index
    int add = 0;
    for (int b = 0; b < pidx; ++b) add += part[b];
    if (i < NODES) {
        const int val = offs[i] + add;
        offs[i]   = val;
        cursor[i] = val;
    }
    if (i == 0) offs[NODES] = EDGES;
}

// ---------------------------------------------------------------------------
// Fused: MFMA projection (blocks 0..781) || CSR scatter (blocks 782..3906).
// Independent: proj needs feat/B; scatter needs cursor (ready before launch).
//
// proj: C[50000][128] = feat @ [Wsrc;Wdst]^T + bias.
// Block = 4 waves x 16 rows = 64 rows; wave = 1 M-frag x 8 N-frags.
// B staged in LDS (double-buffered 32-k slices, shared by 4 waves);
// A register-prefetched one slice ahead. 3-term split-bf16.
// ---------------------------------------------------------------------------
__global__ __launch_bounds__(256) void proj_scatter_kernel(
    const float* __restrict__ feat,
    const short* __restrict__ Bhi, const short* __restrict__ Blo,
    const float* __restrict__ bsrc, const float* __restrict__ bdst,
    float* __restrict__ fs, float* __restrict__ fd,
    const int* __restrict__ src, const int* __restrict__ dst,
    int* __restrict__ cursor, unsigned short* __restrict__ csr)
{
    __shared__ short sB[2][2][512 * 8];            // [buf][plane][unit*8] 32 KB

    if (blockIdx.x >= PROJ_BLOCKS) {
        // ---------------- scatter ----------------
        const int e = (blockIdx.x - PROJ_BLOCKS) * 256 + threadIdx.x;
        if (e < EDGES) {
            const int d   = dst[e];
            const int pos = atomicAdd(&cursor[d], 1);
            csr[pos] = (unsigned short)src[e];
        }
        return;
    }

    // ---------------- proj ----------------
    const int t    = threadIdx.x;
    const int lane = t & 63;
    const int w    = t >> 6;                       // wave 0..3
    const int fr   = lane & 15;
    const int fq   = lane >> 4;                    // k-octet 0..3
    const int fragu = fq * 128 + fr;               // LDS unit base for frags

    // staging ids: thread t stages units t and t+256 per plane
    const int colu = t & 127;
    const int fq0  = t >> 7;                       // 0..1
    const int fq1  = fq0 + 2;                      // 2..3

    const int r0 = blockIdx.x * 64 + w * 16;       // wave's first row
    int rowA = r0 + fr;  if (rowA >= NODES) rowA = NODES - 1;
    const float* pA = feat + (size_t)rowA * FIN + fq * 8;

    f32x4 acc[8];
#pragma unroll
    for (int n = 0; n < 8; ++n) acc[n] = (f32x4){0.f, 0.f, 0.f, 0.f};

    float4 bs00, bs01, bs10, bs11;                 // B stage regs
    float4 acA, acB, anA, anB;                     // A current / next

#define B_ISSUE(kslice) do {                                                  \
        const size_t o0 = (size_t)colu * FIN + (kslice) * 32 + fq0 * 8;       \
        const size_t o1 = (size_t)colu * FIN + (kslice) * 32 + fq1 * 8;       \
        bs00 = *(const float4*)(Bhi + o0);  bs01 = *(const float4*)(Bhi + o1);\
        bs10 = *(const float4*)(Blo + o0);  bs11 = *(const float4*)(Blo + o1);\
    } while (0)

#define B_WRITE(buf) do {                                                     \
        *(float4*)&sB[buf][0][(size_t)t * 8]         = bs00;                  \
        *(float4*)&sB[buf][0][(size_t)(t + 256) * 8] = bs01;                  \
        *(float4*)&sB[buf][1][(size_t)t * 8]         = bs10;                  \
        *(float4*)&sB[buf][1][(size_t)(t + 256) * 8] = bs11;                  \
    } while (0)

#define A_LOAD(dA, dB, kslice) do {                                           \
        dA = *(const float4*)(pA + (kslice) * 32);                            \
        dB = *(const float4*)(pA + (kslice) * 32 + 4);                        \
    } while (0)

#define COMPUTE(buf, AH, AL) do {                                             \
        _Pragma("unroll")                                                     \
        for (int nf = 0; nf < 8; ++nf) {                                      \
            const bf16x8 bh = *(const bf16x8*)&sB[buf][0][(fragu + nf*16)*8]; \
            const bf16x8 bl = *(const bf16x8*)&sB[buf][1][(fragu + nf*16)*8]; \
            acc[nf] = __builtin_amdgcn_mfma_f32_16x16x32_bf16(AH, bh, acc[nf], 0, 0, 0); \
            acc[nf] = __builtin_amdgcn_mfma_f32_16x16x32_bf16(AL, bh, acc[nf], 0, 0, 0); \
            acc[nf] = __builtin_amdgcn_mfma_f32_16x16x32_bf16(AH, bl, acc[nf], 0, 0, 0); \
        } } while (0)

    // prologue: stage slice 0, load A slice 0
    B_ISSUE(0);
    A_LOAD(acA, acB, 0);
    B_WRITE(0);
    __syncthreads();

    for (int ks2 = 0; ks2 < 8; ks2 += 2) {
        const int k1 = (ks2 + 1 < 7) ? ks2 + 1 : 7;
        const int k2 = (ks2 + 2 < 7) ? ks2 + 2 : 7;
        bf16x8 ah, al;

        // even phase: compute slice ks2 from buf0; stage k1 -> buf1
        B_ISSUE(k1);
        A_LOAD(anA, anB, k1);
        split8(acA, acB, ah, al);
        COMPUTE(0, ah, al);
        B_WRITE(1);
        __syncthreads();

        // odd phase: compute slice ks2+1 from buf1; stage k2 -> buf0
        B_ISSUE(k2);
        A_LOAD(acA, acB, k2);
        split8(anA, anB, ah, al);
        COMPUTE(1, ah, al);
        B_WRITE(0);
        __syncthreads();
    }

    // epilogue: bias + store.  D: row = fq*4+r, col = fr (m89/m91 mapping)
#pragma unroll
    for (int nf = 0; nf < 8; ++nf) {
        float* outp = (nf < 4) ? fs : fd;
        const float bias = ((nf < 4) ? bsrc : bdst)[(nf & 3) * 16 + fr];
        const int c = (nf & 3) * 16 + fr;
#pragma unroll
        for (int r = 0; r < 4; ++r) {
            const int row = r0 + fq * 4 + r;
            if (row < NODES)
                outp[(size_t)row * HD + c] = acc[nf][r] + bias;
        }
    }
#undef B_ISSUE
#undef B_WRITE
#undef A_LOAD
#undef COMPUTE
}

// ---------------------------------------------------------------------------
// Per-destination-node GAT: one wave per node, lane = h*16+d.
// No max-subtraction (scores bounded; exp(s)/sum exp(s) identical math).
// Head reduce via DPP (VALU), edge broadcast via readlane, 4-edge unroll.
// ---------------------------------------------------------------------------
__device__ __forceinline__ float head_sum16(float x)
{
    x += __int_as_float(__builtin_amdgcn_update_dpp(0, __float_as_int(x), 0xB1,  0xf, 0xf, true)); // ^1
    x += __int_as_float(__builtin_amdgcn_update_dpp(0, __float_as_int(x), 0x4E,  0xf, 0xf, true)); // ^2
    x += __int_as_float(__builtin_amdgcn_update_dpp(0, __float_as_int(x), 0x141, 0xf, 0xf, true)); // half-mirror
    x += __int_as_float(__builtin_amdgcn_update_dpp(0, __float_as_int(x), 0x140, 0xf, 0xf, true)); // mirror
    return x;
}

__global__ __launch_bounds__(256) void gat_kernel(
    const float* __restrict__ fs, const float* __restrict__ fd,
    const float* __restrict__ attn,
    const int* __restrict__ offs, const unsigned short* __restrict__ csr,
    float* __restrict__ out)
{
    const int wid  = (blockIdx.x * blockDim.x + threadIdx.x) >> 6;  // node id
    const int lane = threadIdx.x & 63;
    if (wid >= NODES) return;

    const float er = fd[(size_t)wid * HD + lane];
    const float aw = attn[lane];
    const int start = __builtin_amdgcn_readfirstlane(offs[wid]);
    const int end   = __builtin_amdgcn_readfirstlane(offs[wid + 1]);

    float s = 0.f, acc = 0.f;

    for (int base = start; base < end; base += 64) {
        const int rem = end - base;
        const int cnt = rem < 64 ? rem : 64;
        int srcv = 0;
        if (lane < cnt) srcv = (int)csr[base + lane];

        int j = 0;
        for (; j + 4 <= cnt; j += 4) {
            const int i0 = __builtin_amdgcn_readlane(srcv, j + 0);
            const int i1 = __builtin_amdgcn_readlane(srcv, j + 1);
            const int i2 = __builtin_amdgcn_readlane(srcv, j + 2);
            const int i3 = __builtin_amdgcn_readlane(srcv, j + 3);
            const float el0 = fs[(size_t)i0 * HD + lane];
            const float el1 = fs[(size_t)i1 * HD + lane];
            const float el2 = fs[(size_t)i2 * HD + lane];
            const float el3 = fs[(size_t)i3 * HD + lane];
            const float t0 = el0 + er, t1 = el1 + er, t2 = el2 + er, t3 = el3 + er;
            const float e0 = fmaf(NEG, fminf(t0, 0.f), fmaxf(t0, 0.f));
            const float e1 = fmaf(NEG, fminf(t1, 0.f), fmaxf(t1, 0.f));
            const float e2 = fmaf(NEG, fminf(t2, 0.f), fmaxf(t2, 0.f));
            const float e3 = fmaf(NEG, fminf(t3, 0.f), fmaxf(t3, 0.f));
            const float p0 = head_sum16(e0 * aw);
            const float p1 = head_sum16(e1 * aw);
            const float p2 = head_sum16(e2 * aw);
            const float p3 = head_sum16(e3 * aw);
            const float pe0 = __expf(p0);
            const float pe1 = __expf(p1);
            const float pe2 = __expf(p2);
            const float pe3 = __expf(p3);
            s += (pe0 + pe1) + (pe2 + pe3);
            acc = fmaf(pe0, el0, fmaf(pe1, el1, fmaf(pe2, el2, fmaf(pe3, el3, acc))));
        }
        for (; j < cnt; ++j) {
            const int i0 = __builtin_amdgcn_readlane(srcv, j);
            const float el0 = fs[(size_t)i0 * HD + lane];
            const float t0 = el0 + er;
            const float e0 = fmaf(NEG, fminf(t0, 0.f), fmaxf(t0, 0.f));
            const float pe0 = __expf(head_sum16(e0 * aw));
            s += pe0;
            acc = fmaf(pe0, el0, acc);
        }
    }
    out[(size_t)wid * HD + lane] = (end > start) ? (acc / s) : 0.f;
}

// ---------------------------------------------------------------------------
extern "C" void kernel_launch(void* const* d_in, const int* in_sizes, int n_in,
                              void* d_out, int out_size, void* d_ws, size_t ws_size,
                              hipStream_t stream)
{
    const float* feat = (const float*)d_in[0];
    const int*   src  = (const int*)  d_in[1];
    const int*   dst  = (const int*)  d_in[2];
    const float* Wsrc = (const float*)d_in[3];
    const float* bsrc = (const float*)d_in[4];
    const float* Wdst = (const float*)d_in[5];
    const float* bdst = (const float*)d_in[6];
    const float* attn = (const float*)d_in[7];
    float* out = (float*)d_out;

    // workspace layout (~27.9 MB)
    float* fs     = (float*)d_ws;                    // N*64 f32
    float* fd     = fs + (size_t)NODES * HD;         // N*64 f32
    int*   offs   = (int*)(fd + (size_t)NODES * HD); // N+1 (+pad)
    int*   deg    = offs + (NODES + 16);             // N
    int*   cursor = deg + NODES;                     // N
    int*   part   = cursor + NODES;                  // 64
    unsigned short* csr = (unsigned short*)(part + 64); // E ushort
    short* Bhi    = (short*)(csr + EDGES);           // 128*256 bf16
    short* Blo    = Bhi + 128 * FIN;                 // 128*256 bf16

    const int scan_blocks = (NODES + 1023) / 1024;   // 49

    hipMemsetAsync(deg, 0, NODES * sizeof(int), stream);

    prep_hist_kernel<<<PREP_BLOCKS + HIST_BLOCKS, 256, 0, stream>>>(
        Wsrc, Wdst, Bhi, Blo, dst, deg);
    scan1_kernel<<<scan_blocks, 256, 0, stream>>>(deg, offs, part);
    scan3_kernel<<<(NODES + 255) / 256, 256, 0, stream>>>(offs, part, cursor);
    proj_scatter_kernel<<<PROJ_BLOCKS + SCAT_BLOCKS, 256, 0, stream>>>(
        feat, Bhi, Blo, bsrc, bdst, fs, fd, src, dst, cursor, csr);
    gat_kernel<<<((size_t)NODES * 64 + 255) / 256, 256, 0, stream>>>(
        fs, fd, attn, offs, csr, out);
}

// Round 10
// 223.500 us; speedup vs baseline: 1.2125x; 1.0870x over previous
//
#include <hip/hip_runtime.h>
#include <math.h>

#define NODES 50000
#define EDGES 800000
#define FIN   256
#define HD    64      // H*D = 4*16
#define NEG   0.2f

#define PROJ_BLOCKS 782          // ceil(50000/64) : 64 rows per block
#define NB          196          // dst buckets (dst>>8), ceil(50000/256)
#define STAGE_BLOCKS 196         // ceil(800000/4096), 4096 edges per block
#define PREP_BLOCKS 128          // 32768/256
#define HIST_BLOCKS 3125

typedef __attribute__((ext_vector_type(8))) short bf16x8;
typedef __attribute__((ext_vector_type(4))) float f32x4;

// ---------------------------------------------------------------------------
// Split fp32 -> hi/lo bf16 (truncation split; exact residual).
// ---------------------------------------------------------------------------
__device__ __forceinline__ unsigned pack_hi(unsigned a, unsigned b)
{ return (a >> 16) | (b & 0xFFFF0000u); }

__device__ __forceinline__ void split8(const float4 x01, const float4 x23,
                                       bf16x8& hi, bf16x8& lo)
{
    const float xs[8] = { x01.x, x01.y, x01.z, x01.w, x23.x, x23.y, x23.z, x23.w };
    union { unsigned w[4]; bf16x8 v; } H, L;
#pragma unroll
    for (int p = 0; p < 4; ++p) {
        const float a = xs[2 * p], b = xs[2 * p + 1];
        const unsigned ba = __float_as_uint(a), bb = __float_as_uint(b);
        H.w[p] = pack_hi(ba, bb);
        const float la = a - __uint_as_float(ba & 0xFFFF0000u);
        const float lb = b - __uint_as_float(bb & 0xFFFF0000u);
        L.w[p] = pack_hi(__float_as_uint(la), __float_as_uint(lb));
    }
    hi = H.v; lo = L.v;
}

// ---------------------------------------------------------------------------
// Fused: prep_b (blocks 0..127) || hist (blocks 128..3252). Independent work.
// ---------------------------------------------------------------------------
__global__ void prep_hist_kernel(const float* __restrict__ Wsrc,
                                 const float* __restrict__ Wdst,
                                 short* __restrict__ Bhi, short* __restrict__ Blo,
                                 const int* __restrict__ dst, int* __restrict__ deg)
{
    const int b = blockIdx.x;
    if (b < PREP_BLOCKS) {
        const int i = b * 256 + threadIdx.x;            // 0..32767
        const int row = i >> 8, k = i & 255;
        const float x = (row < 64) ? Wsrc[row * FIN + k] : Wdst[(row - 64) * FIN + k];
        const unsigned bb = __float_as_uint(x);
        const float l = x - __uint_as_float(bb & 0xFFFF0000u);
        Bhi[i] = (short)(bb >> 16);
        Blo[i] = (short)(__float_as_uint(l) >> 16);
    } else {
        const int e = (b - PREP_BLOCKS) * 256 + threadIdx.x;
        if (e < EDGES) atomicAdd(&deg[dst[e]], 1);
    }
}

// ---------------------------------------------------------------------------
// CSR scan: scan1 (per-1024 chunk) -> scan3 (adds raw partials).
// scan3 also seeds bcur[b] = offs[256*b] for the bucket-stage pass.
// ---------------------------------------------------------------------------
__global__ void scan1_kernel(const int* __restrict__ deg, int* __restrict__ offs,
                             int* __restrict__ part)
{
    __shared__ int lds[256];
    const int t  = threadIdx.x;
    const int i0 = blockIdx.x * 1024 + t * 4;
    int v[4];
#pragma unroll
    for (int k = 0; k < 4; ++k) v[k] = (i0 + k < NODES) ? deg[i0 + k] : 0;
    const int tsum = v[0] + v[1] + v[2] + v[3];
    lds[t] = tsum;
    __syncthreads();
    for (int off = 1; off < 256; off <<= 1) {
        const int x = (t >= off) ? lds[t - off] : 0;
        __syncthreads();
        lds[t] += x;
        __syncthreads();
    }
    const int excl = lds[t] - tsum;
    int run = excl;
#pragma unroll
    for (int k = 0; k < 4; ++k) {
        if (i0 + k < NODES) offs[i0 + k] = run;
        run += v[k];
    }
    if (t == 255) part[blockIdx.x] = lds[255];   // inclusive chunk total
}

__global__ void scan3_kernel(int* __restrict__ offs, const int* __restrict__ part,
                             int* __restrict__ bcur)
{
    const int i = blockIdx.x * blockDim.x + threadIdx.x;
    const int pidx = blockIdx.x >> 2;            // block-uniform chunk index
    int add = 0;
    for (int b = 0; b < pidx; ++b) add += part[b];
    if (i < NODES) {
        const int val = offs[i] + add;
        offs[i] = val;
        if ((i & 255) == 0) bcur[i >> 8] = val;  // bucket base = offs[256b]
    }
    if (i == 0) offs[NODES] = EDGES;
}

// ---------------------------------------------------------------------------
// Fused: MFMA projection (blocks 0..781) || bucket-stage (782..977).
//
// proj: C[50000][128] = feat @ [Wsrc;Wdst]^T + bias (3-term split-bf16,
// B LDS-double-buffered per 32-k slice, A register-prefetched).
//
// stage: 4096 edges/block. LDS hist over 196 dst-buckets -> one global
// atomicAdd per (block,bucket) reserves a contiguous run at bcur[b] ->
// packed (src | dlow<<16) written in ~contiguous runs. Kills the 41 MB of
// random-2B-write line amplification the old scatter paid.
// ---------------------------------------------------------------------------
__global__ __launch_bounds__(256) void proj_stage_kernel(
    const float* __restrict__ feat,
    const short* __restrict__ Bhi, const short* __restrict__ Blo,
    const float* __restrict__ bsrc, const float* __restrict__ bdst,
    float* __restrict__ fs, float* __restrict__ fd,
    const int* __restrict__ src, const int* __restrict__ dst,
    int* __restrict__ bcur, unsigned* __restrict__ bedge)
{
    __shared__ short sB[2][2][512 * 8];            // [buf][plane][unit*8] 32 KB
    __shared__ int   sH[NB], sBase[NB];            // stage-pass bins

    const int t = threadIdx.x;

    if (blockIdx.x >= PROJ_BLOCKS) {
        // ---------------- bucket-stage ----------------
        const int e0 = (blockIdx.x - PROJ_BLOCKS) * 4096;
        for (int i = t; i < NB; i += 256) sH[i] = 0;
        __syncthreads();
#pragma unroll
        for (int k = 0; k < 16; ++k) {
            const int e = e0 + k * 256 + t;
            if (e < EDGES) atomicAdd(&sH[dst[e] >> 8], 1);
        }
        __syncthreads();
        for (int i = t; i < NB; i += 256) {
            const int c = sH[i];
            sBase[i] = c ? atomicAdd(&bcur[i], c) : 0;
            sH[i] = 0;
        }
        __syncthreads();
#pragma unroll
        for (int k = 0; k < 16; ++k) {
            const int e = e0 + k * 256 + t;
            if (e < EDGES) {
                const int d = dst[e];
                const int b = d >> 8;
                const int p = sBase[b] + atomicAdd(&sH[b], 1);
                bedge[p] = (unsigned)src[e] | ((unsigned)(d & 255) << 16);
            }
        }
        return;
    }

    // ---------------- proj ----------------
    const int lane = t & 63;
    const int w    = t >> 6;                       // wave 0..3
    const int fr   = lane & 15;
    const int fq   = lane >> 4;                    // k-octet 0..3
    const int fragu = fq * 128 + fr;               // LDS unit base for frags

    // staging ids: thread t stages units t and t+256 per plane
    const int colu = t & 127;
    const int fq0  = t >> 7;                       // 0..1
    const int fq1  = fq0 + 2;                      // 2..3

    const int r0 = blockIdx.x * 64 + w * 16;       // wave's first row
    int rowA = r0 + fr;  if (rowA >= NODES) rowA = NODES - 1;
    const float* pA = feat + (size_t)rowA * FIN + fq * 8;

    f32x4 acc[8];
#pragma unroll
    for (int n = 0; n < 8; ++n) acc[n] = (f32x4){0.f, 0.f, 0.f, 0.f};

    float4 bs00, bs01, bs10, bs11;                 // B stage regs
    float4 acA, acB, anA, anB;                     // A current / next

#define B_ISSUE(kslice) do {                                                  \
        const size_t o0 = (size_t)colu * FIN + (kslice) * 32 + fq0 * 8;       \
        const size_t o1 = (size_t)colu * FIN + (kslice) * 32 + fq1 * 8;       \
        bs00 = *(const float4*)(Bhi + o0);  bs01 = *(const float4*)(Bhi + o1);\
        bs10 = *(const float4*)(Blo + o0);  bs11 = *(const float4*)(Blo + o1);\
    } while (0)

#define B_WRITE(buf) do {                                                     \
        *(float4*)&sB[buf][0][(size_t)t * 8]         = bs00;                  \
        *(float4*)&sB[buf][0][(size_t)(t + 256) * 8] = bs01;                  \
        *(float4*)&sB[buf][1][(size_t)t * 8]         = bs10;                  \
        *(float4*)&sB[buf][1][(size_t)(t + 256) * 8] = bs11;                  \
    } while (0)

#define A_LOAD(dA, dB, kslice) do {                                           \
        dA = *(const float4*)(pA + (kslice) * 32);                            \
        dB = *(const float4*)(pA + (kslice) * 32 + 4);                        \
    } while (0)

#define COMPUTE(buf, AH, AL) do {                                             \
        _Pragma("unroll")                                                     \
        for (int nf = 0; nf < 8; ++nf) {                                      \
            const bf16x8 bh = *(const bf16x8*)&sB[buf][0][(fragu + nf*16)*8]; \
            const bf16x8 bl = *(const bf16x8*)&sB[buf][1][(fragu + nf*16)*8]; \
            acc[nf] = __builtin_amdgcn_mfma_f32_16x16x32_bf16(AH, bh, acc[nf], 0, 0, 0); \
            acc[nf] = __builtin_amdgcn_mfma_f32_16x16x32_bf16(AL, bh, acc[nf], 0, 0, 0); \
            acc[nf] = __builtin_amdgcn_mfma_f32_16x16x32_bf16(AH, bl, acc[nf], 0, 0, 0); \
        } } while (0)

    // prologue: stage slice 0, load A slice 0
    B_ISSUE(0);
    A_LOAD(acA, acB, 0);
    B_WRITE(0);
    __syncthreads();

    for (int ks2 = 0; ks2 < 8; ks2 += 2) {
        const int k1 = (ks2 + 1 < 7) ? ks2 + 1 : 7;
        const int k2 = (ks2 + 2 < 7) ? ks2 + 2 : 7;
        bf16x8 ah, al;

        // even phase: compute slice ks2 from buf0; stage k1 -> buf1
        B_ISSUE(k1);
        A_LOAD(anA, anB, k1);
        split8(acA, acB, ah, al);
        COMPUTE(0, ah, al);
        B_WRITE(1);
        __syncthreads();

        // odd phase: compute slice ks2+1 from buf1; stage k2 -> buf0
        B_ISSUE(k2);
        A_LOAD(acA, acB, k2);
        split8(anA, anB, ah, al);
        COMPUTE(1, ah, al);
        B_WRITE(0);
        __syncthreads();
    }

    // epilogue: bias + store.  D: row = fq*4+r, col = fr (m89/m91 mapping)
#pragma unroll
    for (int nf = 0; nf < 8; ++nf) {
        float* outp = (nf < 4) ? fs : fd;
        const float bias = ((nf < 4) ? bsrc : bdst)[(nf & 3) * 16 + fr];
        const int c = (nf & 3) * 16 + fr;
#pragma unroll
        for (int r = 0; r < 4; ++r) {
            const int row = r0 + fq * 4 + r;
            if (row < NODES)
                outp[(size_t)row * HD + c] = acc[nf][r] + bias;
        }
    }
#undef B_ISSUE
#undef B_WRITE
#undef A_LOAD
#undef COMPUTE
}

// ---------------------------------------------------------------------------
// Bucket scatter: one block per bucket; per-node cursors in LDS; all csr
// writes land in the bucket's 8 KB region on one XCD -> amplification ~1.
// ---------------------------------------------------------------------------
__global__ __launch_bounds__(256) void bucket_scatter_kernel(
    const int* __restrict__ offs, const unsigned* __restrict__ bedge,
    unsigned short* __restrict__ csr)
{
    __shared__ int cur[256];
    const int b  = blockIdx.x;                     // 0..195
    const int t  = threadIdx.x;
    const int n0 = b * 256;
    const int start = offs[n0];                    // block-uniform
    const int node  = n0 + t;
    cur[t] = ((node < NODES) ? offs[node] : EDGES) - start;
    __syncthreads();
    const int end = (n0 + 256 <= NODES) ? offs[n0 + 256] : EDGES;
    for (int i = start + t; i < end; i += 256) {
        const unsigned pk = bedge[i];
        const int rel = atomicAdd(&cur[(pk >> 16) & 255], 1);
        csr[start + rel] = (unsigned short)(pk & 0xFFFFu);
    }
}

// ---------------------------------------------------------------------------
// Per-destination-node GAT: one wave per node, lane = h*16+d.
// No max-subtraction (scores bounded; exp(s)/sum exp(s) identical math).
// Head reduce via DPP (VALU), edge broadcast via readlane, 4-edge unroll.
// ---------------------------------------------------------------------------
__device__ __forceinline__ float head_sum16(float x)
{
    x += __int_as_float(__builtin_amdgcn_update_dpp(0, __float_as_int(x), 0xB1,  0xf, 0xf, true)); // ^1
    x += __int_as_float(__builtin_amdgcn_update_dpp(0, __float_as_int(x), 0x4E,  0xf, 0xf, true)); // ^2
    x += __int_as_float(__builtin_amdgcn_update_dpp(0, __float_as_int(x), 0x141, 0xf, 0xf, true)); // half-mirror
    x += __int_as_float(__builtin_amdgcn_update_dpp(0, __float_as_int(x), 0x140, 0xf, 0xf, true)); // mirror
    return x;
}

__global__ __launch_bounds__(256) void gat_kernel(
    const float* __restrict__ fs, const float* __restrict__ fd,
    const float* __restrict__ attn,
    const int* __restrict__ offs, const unsigned short* __restrict__ csr,
    float* __restrict__ out)
{
    const int wid  = (blockIdx.x * blockDim.x + threadIdx.x) >> 6;  // node id
    const int lane = threadIdx.x & 63;
    if (wid >= NODES) return;

    const float er = fd[(size_t)wid * HD + lane];
    const float aw = attn[lane];
    const int start = __builtin_amdgcn_readfirstlane(offs[wid]);
    const int end   = __builtin_amdgcn_readfirstlane(offs[wid + 1]);

    float s = 0.f, acc = 0.f;

    for (int base = start; base < end; base += 64) {
        const int rem = end - base;
        const int cnt = rem < 64 ? rem : 64;
        int srcv = 0;
        if (lane < cnt) srcv = (int)csr[base + lane];

        int j = 0;
        for (; j + 4 <= cnt; j += 4) {
            const int i0 = __builtin_amdgcn_readlane(srcv, j + 0);
            const int i1 = __builtin_amdgcn_readlane(srcv, j + 1);
            const int i2 = __builtin_amdgcn_readlane(srcv, j + 2);
            const int i3 = __builtin_amdgcn_readlane(srcv, j + 3);
            const float el0 = fs[(size_t)i0 * HD + lane];
            const float el1 = fs[(size_t)i1 * HD + lane];
            const float el2 = fs[(size_t)i2 * HD + lane];
            const float el3 = fs[(size_t)i3 * HD + lane];
            const float t0 = el0 + er, t1 = el1 + er, t2 = el2 + er, t3 = el3 + er;
            const float e0 = fmaf(NEG, fminf(t0, 0.f), fmaxf(t0, 0.f));
            const float e1 = fmaf(NEG, fminf(t1, 0.f), fmaxf(t1, 0.f));
            const float e2 = fmaf(NEG, fminf(t2, 0.f), fmaxf(t2, 0.f));
            const float e3 = fmaf(NEG, fminf(t3, 0.f), fmaxf(t3, 0.f));
            const float p0 = head_sum16(e0 * aw);
            const float p1 = head_sum16(e1 * aw);
            const float p2 = head_sum16(e2 * aw);
            const float p3 = head_sum16(e3 * aw);
            const float pe0 = __expf(p0);
            const float pe1 = __expf(p1);
            const float pe2 = __expf(p2);
            const float pe3 = __expf(p3);
            s += (pe0 + pe1) + (pe2 + pe3);
            acc = fmaf(pe0, el0, fmaf(pe1, el1, fmaf(pe2, el2, fmaf(pe3, el3, acc))));
        }
        for (; j < cnt; ++j) {
            const int i0 = __builtin_amdgcn_readlane(srcv, j);
            const float el0 = fs[(size_t)i0 * HD + lane];
            const float t0 = el0 + er;
            const float e0 = fmaf(NEG, fminf(t0, 0.f), fmaxf(t0, 0.f));
            const float pe0 = __expf(head_sum16(e0 * aw));
            s += pe0;
            acc = fmaf(pe0, el0, acc);
        }
    }
    out[(size_t)wid * HD + lane] = (end > start) ? (acc / s) : 0.f;
}

// ---------------------------------------------------------------------------
extern "C" void kernel_launch(void* const* d_in, const int* in_sizes, int n_in,
                              void* d_out, int out_size, void* d_ws, size_t ws_size,
                              hipStream_t stream)
{
    const float* feat = (const float*)d_in[0];
    const int*   src  = (const int*)  d_in[1];
    const int*   dst  = (const int*)  d_in[2];
    const float* Wsrc = (const float*)d_in[3];
    const float* bsrc = (const float*)d_in[4];
    const float* Wdst = (const float*)d_in[5];
    const float* bdst = (const float*)d_in[6];
    const float* attn = (const float*)d_in[7];
    float* out = (float*)d_out;

    // workspace layout (~31.2 MB)
    float* fs     = (float*)d_ws;                    // N*64 f32
    float* fd     = fs + (size_t)NODES * HD;         // N*64 f32
    int*   offs   = (int*)(fd + (size_t)NODES * HD); // N+1 (+pad)
    int*   deg    = offs + (NODES + 16);             // N
    int*   part   = deg + NODES;                     // 64
    int*   bcur   = part + 64;                       // NB (+pad to 256)
    unsigned* bedge = (unsigned*)(bcur + 256);       // E packed (src|dlow<<16)
    unsigned short* csr = (unsigned short*)(bedge + EDGES); // E ushort
    short* Bhi    = (short*)(csr + EDGES);           // 128*256 bf16
    short* Blo    = Bhi + 128 * FIN;                 // 128*256 bf16

    const int scan_blocks = (NODES + 1023) / 1024;   // 49

    hipMemsetAsync(deg, 0, NODES * sizeof(int), stream);

    prep_hist_kernel<<<PREP_BLOCKS + HIST_BLOCKS, 256, 0, stream>>>(
        Wsrc, Wdst, Bhi, Blo, dst, deg);
    scan1_kernel<<<scan_blocks, 256, 0, stream>>>(deg, offs, part);
    scan3_kernel<<<(NODES + 255) / 256, 256, 0, stream>>>(offs, part, bcur);
    proj_stage_kernel<<<PROJ_BLOCKS + STAGE_BLOCKS, 256, 0, stream>>>(
        feat, Bhi, Blo, bsrc, bdst, fs, fd, src, dst, bcur, bedge);
    bucket_scatter_kernel<<<NB, 256, 0, stream>>>(offs, bedge, csr);
    gat_kernel<<<((size_t)NODES * 64 + 255) / 256, 256, 0, stream>>>(
        fs, fd, attn, offs, csr, out);
}

// Round 11
// 194.599 us; speedup vs baseline: 1.3925x; 1.1485x over previous
//
#include <hip/hip_runtime.h>
#include <math.h>

#define NODES 50000
#define EDGES 800000
#define FIN   256
#define HD    64      // H*D = 4*16
#define NEG   0.2f

#define PROJ_BLOCKS 782          // ceil(50000/64) : 64 rows per block
#define NB          196          // dst buckets (dst>>8), ceil(50000/256)
#define STAGE_BLOCKS 196         // 4096 edges per block
#define PREP_BLOCKS 128          // 32768/256

typedef __attribute__((ext_vector_type(8))) short bf16x8;
typedef __attribute__((ext_vector_type(4))) float f32x4;

// ---------------------------------------------------------------------------
// Split fp32 -> hi/lo bf16 (truncation split; exact residual).
// ---------------------------------------------------------------------------
__device__ __forceinline__ unsigned pack_hi(unsigned a, unsigned b)
{ return (a >> 16) | (b & 0xFFFF0000u); }

__device__ __forceinline__ void split8(const float4 x01, const float4 x23,
                                       bf16x8& hi, bf16x8& lo)
{
    const float xs[8] = { x01.x, x01.y, x01.z, x01.w, x23.x, x23.y, x23.z, x23.w };
    union { unsigned w[4]; bf16x8 v; } H, L;
#pragma unroll
    for (int p = 0; p < 4; ++p) {
        const float a = xs[2 * p], b = xs[2 * p + 1];
        const unsigned ba = __float_as_uint(a), bb = __float_as_uint(b);
        H.w[p] = pack_hi(ba, bb);
        const float la = a - __uint_as_float(ba & 0xFFFF0000u);
        const float lb = b - __uint_as_float(bb & 0xFFFF0000u);
        L.w[p] = pack_hi(__float_as_uint(la), __float_as_uint(lb));
    }
    hi = H.v; lo = L.v;
}

// ---------------------------------------------------------------------------
// Fused: prep_b (blocks 0..127) || bucket-count (128..323).
// Bucket-count: LDS hist over 196 dst-buckets, then one global atomicAdd per
// (block,bucket) -> bcnt. Replaces the 800K-random-atomic per-node histogram.
// ---------------------------------------------------------------------------
__global__ void prep_count_kernel(const float* __restrict__ Wsrc,
                                  const float* __restrict__ Wdst,
                                  short* __restrict__ Bhi, short* __restrict__ Blo,
                                  const int* __restrict__ dst, int* __restrict__ bcnt)
{
    const int b = blockIdx.x;
    const int t = threadIdx.x;
    if (b < PREP_BLOCKS) {
        const int i = b * 256 + t;                      // 0..32767
        const int row = i >> 8, k = i & 255;
        const float x = (row < 64) ? Wsrc[row * FIN + k] : Wdst[(row - 64) * FIN + k];
        const unsigned bb = __float_as_uint(x);
        const float l = x - __uint_as_float(bb & 0xFFFF0000u);
        Bhi[i] = (short)(bb >> 16);
        Blo[i] = (short)(__float_as_uint(l) >> 16);
        return;
    }
    __shared__ int sH[NB];
    for (int i = t; i < NB; i += 256) sH[i] = 0;
    __syncthreads();
    const int e0 = (b - PREP_BLOCKS) * 4096;
#pragma unroll
    for (int k = 0; k < 16; ++k) {
        const int e = e0 + k * 256 + t;
        if (e < EDGES) atomicAdd(&sH[dst[e] >> 8], 1);
    }
    __syncthreads();
    for (int i = t; i < NB; i += 256) {
        const int c = sH[i];
        if (c) atomicAdd(&bcnt[i], c);
    }
}

// ---------------------------------------------------------------------------
// Bucket scan (1 block): bbase = exclusive scan of bcnt (197 entries,
// bbase[196]=EDGES); seeds bcur; writes offs[NODES]=EDGES.
// ---------------------------------------------------------------------------
__global__ void bscan_kernel(const int* __restrict__ bcnt, int* __restrict__ bbase,
                             int* __restrict__ bcur, int* __restrict__ offs)
{
    __shared__ int s[256];
    const int t = threadIdx.x;
    const int v = (t < NB) ? bcnt[t] : 0;
    s[t] = v;
    __syncthreads();
    for (int off = 1; off < 256; off <<= 1) {
        const int x = (t >= off) ? s[t - off] : 0;
        __syncthreads();
        s[t] += x;
        __syncthreads();
    }
    const int excl = s[t] - v;
    if (t <= NB) bbase[t] = excl;      // t==NB -> total == EDGES
    if (t < NB)  bcur[t]  = excl;
    if (t == 0)  offs[NODES] = EDGES;
}

// ---------------------------------------------------------------------------
// Fused: MFMA projection (blocks 0..781) || bucket-stage (782..977).
//
// proj: C[50000][128] = feat @ [Wsrc;Wdst]^T + bias (3-term split-bf16).
// A ring-prefetched 2 K-slices ahead in registers (latency off critical path);
// B LDS-double-buffered per 32-k slice (reg-staged, shared by 4 waves).
//
// stage: LDS hist -> reserve contiguous run via atomicAdd(bcur[b]) -> packed
// (src | dlow<<16) written in ~contiguous runs.
// ---------------------------------------------------------------------------
__global__ __launch_bounds__(256) void proj_stage_kernel(
    const float* __restrict__ feat,
    const short* __restrict__ Bhi, const short* __restrict__ Blo,
    const float* __restrict__ bsrc, const float* __restrict__ bdst,
    float* __restrict__ fs, float* __restrict__ fd,
    const int* __restrict__ src, const int* __restrict__ dst,
    int* __restrict__ bcur, unsigned* __restrict__ bedge)
{
    __shared__ short sB[2][2][512 * 8];            // [buf][plane][unit*8] 32 KB
    __shared__ int   sH[NB], sBase[NB];            // stage-pass bins

    const int t = threadIdx.x;

    if (blockIdx.x >= PROJ_BLOCKS) {
        // ---------------- bucket-stage ----------------
        const int e0 = (blockIdx.x - PROJ_BLOCKS) * 4096;
        for (int i = t; i < NB; i += 256) sH[i] = 0;
        __syncthreads();
#pragma unroll
        for (int k = 0; k < 16; ++k) {
            const int e = e0 + k * 256 + t;
            if (e < EDGES) atomicAdd(&sH[dst[e] >> 8], 1);
        }
        __syncthreads();
        for (int i = t; i < NB; i += 256) {
            const int c = sH[i];
            sBase[i] = c ? atomicAdd(&bcur[i], c) : 0;
            sH[i] = 0;
        }
        __syncthreads();
#pragma unroll
        for (int k = 0; k < 16; ++k) {
            const int e = e0 + k * 256 + t;
            if (e < EDGES) {
                const int d = dst[e];
                const int b = d >> 8;
                const int p = sBase[b] + atomicAdd(&sH[b], 1);
                bedge[p] = (unsigned)src[e] | ((unsigned)(d & 255) << 16);
            }
        }
        return;
    }

    // ---------------- proj ----------------
    const int lane = t & 63;
    const int w    = t >> 6;                       // wave 0..3
    const int fr   = lane & 15;
    const int fq   = lane >> 4;                    // k-octet 0..3
    const int fragu = fq * 128 + fr;               // LDS unit base for frags

    // staging ids: thread t stages units t and t+256 per plane
    const int colu = t & 127;
    const int fq0  = t >> 7;                       // 0..1
    const int fq1  = fq0 + 2;                      // 2..3

    const int r0 = blockIdx.x * 64 + w * 16;       // wave's first row
    int rowA = r0 + fr;  if (rowA >= NODES) rowA = NODES - 1;
    const float* pA = feat + (size_t)rowA * FIN + fq * 8;

    f32x4 acc[8];
#pragma unroll
    for (int n = 0; n < 8; ++n) acc[n] = (f32x4){0.f, 0.f, 0.f, 0.f};

    float4 bs00, bs01, bs10, bs11;                 // B stage regs
    float4 aR[3][2];                               // A slice ring (depth 3)

#define B_ISSUE(kslice) do {                                                  \
        const size_t o0 = (size_t)colu * FIN + (kslice) * 32 + fq0 * 8;       \
        const size_t o1 = (size_t)colu * FIN + (kslice) * 32 + fq1 * 8;       \
        bs00 = *(const float4*)(Bhi + o0);  bs01 = *(const float4*)(Bhi + o1);\
        bs10 = *(const float4*)(Blo + o0);  bs11 = *(const float4*)(Blo + o1);\
    } while (0)

#define B_WRITE(buf) do {                                                     \
        *(float4*)&sB[buf][0][(size_t)t * 8]         = bs00;                  \
        *(float4*)&sB[buf][0][(size_t)(t + 256) * 8] = bs01;                  \
        *(float4*)&sB[buf][1][(size_t)t * 8]         = bs10;                  \
        *(float4*)&sB[buf][1][(size_t)(t + 256) * 8] = bs11;                  \
    } while (0)

#define A_LD(r, kslice) do {                                                  \
        aR[r][0] = *(const float4*)(pA + (kslice) * 32);                      \
        aR[r][1] = *(const float4*)(pA + (kslice) * 32 + 4);                  \
    } while (0)

#define COMPUTE(buf, AH, AL) do {                                             \
        _Pragma("unroll")                                                     \
        for (int nf = 0; nf < 8; ++nf) {                                      \
            const bf16x8 bh = *(const bf16x8*)&sB[buf][0][(fragu + nf*16)*8]; \
            const bf16x8 bl = *(const bf16x8*)&sB[buf][1][(fragu + nf*16)*8]; \
            acc[nf] = __builtin_amdgcn_mfma_f32_16x16x32_bf16(AH, bh, acc[nf], 0, 0, 0); \
            acc[nf] = __builtin_amdgcn_mfma_f32_16x16x32_bf16(AL, bh, acc[nf], 0, 0, 0); \
            acc[nf] = __builtin_amdgcn_mfma_f32_16x16x32_bf16(AH, bl, acc[nf], 0, 0, 0); \
        } } while (0)

    // prologue: stage B slice 0 -> buf0; prefetch A slices 0,1
    B_ISSUE(0);
    A_LD(0, 0);
    A_LD(1, 1);
    B_WRITE(0);
    __syncthreads();

#pragma unroll
    for (int ks = 0; ks < 8; ++ks) {
        const int buf = ks & 1;
        if (ks < 7) B_ISSUE(ks + 1);               // B one slice ahead (regs)
        if (ks < 6) A_LD((ks + 2) % 3, ks + 2);    // A two slices ahead
        bf16x8 ah, al;
        split8(aR[ks % 3][0], aR[ks % 3][1], ah, al);
        COMPUTE(buf, ah, al);
        if (ks < 7) B_WRITE(buf ^ 1);
        __syncthreads();
    }

    // epilogue: bias + store.  D: row = fq*4+r, col = fr (m89/m91 mapping)
#pragma unroll
    for (int nf = 0; nf < 8; ++nf) {
        float* outp = (nf < 4) ? fs : fd;
        const float bias = ((nf < 4) ? bsrc : bdst)[(nf & 3) * 16 + fr];
        const int c = (nf & 3) * 16 + fr;
#pragma unroll
        for (int r = 0; r < 4; ++r) {
            const int row = r0 + fq * 4 + r;
            if (row < NODES)
                outp[(size_t)row * HD + c] = acc[nf][r] + bias;
        }
    }
#undef B_ISSUE
#undef B_WRITE
#undef A_LD
#undef COMPUTE
}

// ---------------------------------------------------------------------------
// Bucket scatter: one block per bucket. Derives per-node degrees from the
// bucket's packed edges (LDS counters), LDS-scans them into offs[], then
// places edges into csr — all traffic confined to the bucket's region.
// Replaces scan1 + scan3 + old scatter.
// ---------------------------------------------------------------------------
__global__ __launch_bounds__(256) void bucket_scatter_kernel(
    const int* __restrict__ bbase, const unsigned* __restrict__ bedge,
    int* __restrict__ offs, unsigned short* __restrict__ csr)
{
    __shared__ int s[256];
    __shared__ int pl[256];
    const int b = blockIdx.x;                      // 0..195
    const int t = threadIdx.x;
    const int start = bbase[b];                    // block-uniform
    const int end   = bbase[b + 1];

    s[t] = 0;
    __syncthreads();
    for (int i = start + t; i < end; i += 256)
        atomicAdd(&s[(bedge[i] >> 16) & 255], 1);
    __syncthreads();

    const int v = s[t];
    __syncthreads();
    for (int off = 1; off < 256; off <<= 1) {
        const int x = (t >= off) ? s[t - off] : 0;
        __syncthreads();
        s[t] += x;
        __syncthreads();
    }
    const int excl = s[t] - v;

    const int node = b * 256 + t;
    if (node < NODES) offs[node] = start + excl;
    pl[t] = excl;
    __syncthreads();

    for (int i = start + t; i < end; i += 256) {
        const unsigned pk = bedge[i];
        const int rel = atomicAdd(&pl[(pk >> 16) & 255], 1);
        csr[start + rel] = (unsigned short)(pk & 0xFFFFu);
    }
}

// ---------------------------------------------------------------------------
// Per-destination-node GAT: one wave per node, lane = h*16+d.
// No max-subtraction (scores bounded; exp(s)/sum exp(s) identical math).
// Head reduce via DPP (VALU), edge broadcast via readlane, 4-edge unroll.
// ---------------------------------------------------------------------------
__device__ __forceinline__ float head_sum16(float x)
{
    x += __int_as_float(__builtin_amdgcn_update_dpp(0, __float_as_int(x), 0xB1,  0xf, 0xf, true)); // ^1
    x += __int_as_float(__builtin_amdgcn_update_dpp(0, __float_as_int(x), 0x4E,  0xf, 0xf, true)); // ^2
    x += __int_as_float(__builtin_amdgcn_update_dpp(0, __float_as_int(x), 0x141, 0xf, 0xf, true)); // half-mirror
    x += __int_as_float(__builtin_amdgcn_update_dpp(0, __float_as_int(x), 0x140, 0xf, 0xf, true)); // mirror
    return x;
}

__global__ __launch_bounds__(256) void gat_kernel(
    const float* __restrict__ fs, const float* __restrict__ fd,
    const float* __restrict__ attn,
    const int* __restrict__ offs, const unsigned short* __restrict__ csr,
    float* __restrict__ out)
{
    const int wid  = (blockIdx.x * blockDim.x + threadIdx.x) >> 6;  // node id
    const int lane = threadIdx.x & 63;
    if (wid >= NODES) return;

    const float er = fd[(size_t)wid * HD + lane];
    const float aw = attn[lane];
    const int start = __builtin_amdgcn_readfirstlane(offs[wid]);
    const int end   = __builtin_amdgcn_readfirstlane(offs[wid + 1]);

    float s = 0.f, acc = 0.f;

    for (int base = start; base < end; base += 64) {
        const int rem = end - base;
        const int cnt = rem < 64 ? rem : 64;
        int srcv = 0;
        if (lane < cnt) srcv = (int)csr[base + lane];

        int j = 0;
        for (; j + 4 <= cnt; j += 4) {
            const int i0 = __builtin_amdgcn_readlane(srcv, j + 0);
            const int i1 = __builtin_amdgcn_readlane(srcv, j + 1);
            const int i2 = __builtin_amdgcn_readlane(srcv, j + 2);
            const int i3 = __builtin_amdgcn_readlane(srcv, j + 3);
            const float el0 = fs[(size_t)i0 * HD + lane];
            const float el1 = fs[(size_t)i1 * HD + lane];
            const float el2 = fs[(size_t)i2 * HD + lane];
            const float el3 = fs[(size_t)i3 * HD + lane];
            const float t0 = el0 + er, t1 = el1 + er, t2 = el2 + er, t3 = el3 + er;
            const float e0 = fmaf(NEG, fminf(t0, 0.f), fmaxf(t0, 0.f));
            const float e1 = fmaf(NEG, fminf(t1, 0.f), fmaxf(t1, 0.f));
            const float e2 = fmaf(NEG, fminf(t2, 0.f), fmaxf(t2, 0.f));
            const float e3 = fmaf(NEG, fminf(t3, 0.f), fmaxf(t3, 0.f));
            const float p0 = head_sum16(e0 * aw);
            const float p1 = head_sum16(e1 * aw);
            const float p2 = head_sum16(e2 * aw);
            const float p3 = head_sum16(e3 * aw);
            const float pe0 = __expf(p0);
            const float pe1 = __expf(p1);
            const float pe2 = __expf(p2);
            const float pe3 = __expf(p3);
            s += (pe0 + pe1) + (pe2 + pe3);
            acc = fmaf(pe0, el0, fmaf(pe1, el1, fmaf(pe2, el2, fmaf(pe3, el3, acc))));
        }
        for (; j < cnt; ++j) {
            const int i0 = __builtin_amdgcn_readlane(srcv, j);
            const float el0 = fs[(size_t)i0 * HD + lane];
            const float t0 = el0 + er;
            const float e0 = fmaf(NEG, fminf(t0, 0.f), fmaxf(t0, 0.f));
            const float pe0 = __expf(head_sum16(e0 * aw));
            s += pe0;
            acc = fmaf(pe0, el0, acc);
        }
    }
    out[(size_t)wid * HD + lane] = (end > start) ? (acc / s) : 0.f;
}

// ---------------------------------------------------------------------------
extern "C" void kernel_launch(void* const* d_in, const int* in_sizes, int n_in,
                              void* d_out, int out_size, void* d_ws, size_t ws_size,
                              hipStream_t stream)
{
    const float* feat = (const float*)d_in[0];
    const int*   src  = (const int*)  d_in[1];
    const int*   dst  = (const int*)  d_in[2];
    const float* Wsrc = (const float*)d_in[3];
    const float* bsrc = (const float*)d_in[4];
    const float* Wdst = (const float*)d_in[5];
    const float* bdst = (const float*)d_in[6];
    const float* attn = (const float*)d_in[7];
    float* out = (float*)d_out;

    // workspace layout (~31 MB)
    float* fs     = (float*)d_ws;                    // N*64 f32
    float* fd     = fs + (size_t)NODES * HD;         // N*64 f32
    int*   offs   = (int*)(fd + (size_t)NODES * HD); // N+1 (+pad)
    int*   bcnt   = offs + (NODES + 16);             // 256
    int*   bbase  = bcnt + 256;                      // 256 (197 used)
    int*   bcur   = bbase + 256;                     // 256
    unsigned* bedge = (unsigned*)(bcur + 256);       // E packed (src|dlow<<16)
    unsigned short* csr = (unsigned short*)(bedge + EDGES); // E ushort
    short* Bhi    = (short*)(csr + EDGES);           // 128*256 bf16
    short* Blo    = Bhi + 128 * FIN;                 // 128*256 bf16

    hipMemsetAsync(bcnt, 0, 256 * sizeof(int), stream);

    prep_count_kernel<<<PREP_BLOCKS + STAGE_BLOCKS, 256, 0, stream>>>(
        Wsrc, Wdst, Bhi, Blo, dst, bcnt);
    bscan_kernel<<<1, 256, 0, stream>>>(bcnt, bbase, bcur, offs);
    proj_stage_kernel<<<PROJ_BLOCKS + STAGE_BLOCKS, 256, 0, stream>>>(
        feat, Bhi, Blo, bsrc, bdst, fs, fd, src, dst, bcur, bedge);
    bucket_scatter_kernel<<<NB, 256, 0, stream>>>(bbase, bedge, offs, csr);
    gat_kernel<<<((size_t)NODES * 64 + 255) / 256, 256, 0, stream>>>(
        fs, fd, attn, offs, csr, out);
}